// Round 7
// baseline (92.416 us; speedup 1.0000x reference)
//
#include <hip/hip_runtime.h>
#include <hip/hip_bf16.h>
#include <math.h>

#define N_ROWS 4096
#define D 512
#define TWO_N 8192
#define PANELS 64               /* 8192 / 128 row-panels */
#define NPAIRS_P 2080           /* 64*65/2 */
#define GEMM_BLOCKS 256
#define NSLOT 128               /* S16 slots: 2 per panel (wave halves) */
#define INV_T 5.0f

typedef __attribute__((ext_vector_type(8))) __bf16 bf16x8;
typedef __attribute__((ext_vector_type(4))) float f32x4;
#define AS1 __attribute__((address_space(1)))
#define AS3 __attribute__((address_space(3)))

// ---------------- block reduction helper (broadcasts result) ----------------
template<int K>
__device__ inline void block_reduce_bcast(float (&v)[K]) {
  __shared__ float red[4][K];
  const int t = threadIdx.x;
  #pragma unroll
  for (int off = 32; off; off >>= 1)
    #pragma unroll
    for (int i = 0; i < K; ++i) v[i] += __shfl_xor(v[i], off, 64);
  __syncthreads();
  if ((t & 63) == 0)
    #pragma unroll
    for (int i = 0; i < K; ++i) red[t >> 6][i] = v[i];
  __syncthreads();
  #pragma unroll
  for (int i = 0; i < K; ++i) v[i] = red[0][i] + red[1][i] + red[2][i] + red[3][i];
}

// ---------------- kernel 1: normalize rows, emit bf16 reps + fp32 stats ----
__global__ __launch_bounds__(256) void normalize_kernel(
    const float* __restrict__ ei_, const float* __restrict__ ej_,
    const float* __restrict__ ek_,
    __hip_bfloat16* __restrict__ reps, float* __restrict__ diagexp,
    float* __restrict__ pos_ij, float* __restrict__ exp_ik)
{
  const int n = blockIdx.x;
  const int t = threadIdx.x;
  const long base = (long)n * D + 2 * t;
  const float2 ei = *reinterpret_cast<const float2*>(ei_ + base);
  const float2 ej = *reinterpret_cast<const float2*>(ej_ + base);
  const float2 ek = *reinterpret_cast<const float2*>(ek_ + base);

  float v[5];
  v[0] = ei.x * ei.x + ei.y * ei.y;
  v[1] = ej.x * ej.x + ej.y * ej.y;
  v[2] = ek.x * ek.x + ek.y * ek.y;
  v[3] = ei.x * ej.x + ei.y * ej.y;
  v[4] = ek.x * ei.x + ek.y * ei.y;
  block_reduce_bcast<5>(v);

  const float ni = fmaxf(sqrtf(v[0]), 1e-12f);
  const float nj = fmaxf(sqrtf(v[1]), 1e-12f);
  const float nk = fmaxf(sqrtf(v[2]), 1e-12f);
  const float invi = 1.0f / ni, invj = 1.0f / nj;

  __hip_bfloat162 pi, pj;
  pi.x = __float2bfloat16(ei.x * invi);
  pi.y = __float2bfloat16(ei.y * invi);
  pj.x = __float2bfloat16(ej.x * invj);
  pj.y = __float2bfloat16(ej.y * invj);
  *reinterpret_cast<__hip_bfloat162*>(reps + (long)n * D + 2 * t) = pi;
  *reinterpret_cast<__hip_bfloat162*>(reps + (long)(N_ROWS + n) * D + 2 * t) = pj;

  float q[2];
  {
    float f0 = __bfloat162float(pi.x), f1 = __bfloat162float(pi.y);
    q[0] = f0 * f0 + f1 * f1;
    f0 = __bfloat162float(pj.x); f1 = __bfloat162float(pj.y);
    q[1] = f0 * f0 + f1 * f1;
  }
  block_reduce_bcast<2>(q);

  if (t == 0) {
    diagexp[n]          = __expf(INV_T * q[0]);
    diagexp[N_ROWS + n] = __expf(INV_T * q[1]);
    pos_ij[n] = v[3] / (ni * nj);
    exp_ik[n] = __expf(INV_T * v[4] / (nk * ni));
  }
}

// ---------------- kernel 2: reduce the two scalars --------------------------
__global__ __launch_bounds__(256) void scalar_kernel(
    const float* __restrict__ pos_ij, const float* __restrict__ exp_ik,
    float* __restrict__ scalars)
{
  const int t = threadIdx.x;
  float v[2] = {0.f, 0.f};
  for (int i = t; i < N_ROWS; i += 256) { v[0] += pos_ij[i]; v[1] += exp_ik[i]; }
  block_reduce_bcast<2>(v);
  if (t == 0) { scalars[0] = v[0]; scalars[1] = v[1]; }
}

// ---------------- kernel 3: A-panel-resident fused Z*Z^T + exp + sums ------
// 256 blocks x 256 threads (4 waves, 2x2 over a 128x128 tile).
// LDS (163840 B): A-panel [0,131072): [128 rows][64 slots of 16B], swizzled
//                 B dbuf  [131072,163840): [2][128 rows][8 slots of 16B]
// Block processes a contiguous chunk of triangular panel pairs (I<=J) in
// I-major order; A restaged only when I changes.
// Output: bf16 partial sums, slot = 2*panel + wave-half; each (slot,row)
// has exactly one writer: row-sums of pair (P,X) -> slot 2X+wc, rows of P
// (P<=X); col-sums of pair (X,P) -> slot 2X+wr, rows of P (X<P). Full cover.
__global__ __launch_bounds__(256) void gemm_apanel_kernel(
    const __hip_bfloat16* __restrict__ reps, __hip_bfloat16* __restrict__ S16)
{
  extern __shared__ __align__(128) char smem[];
  char* Abase = smem;
  char* Bbase = smem + 131072;

  const int t = threadIdx.x;
  const int l = t & 63;
  const int w = t >> 6;          // wave 0..3
  const int wr = w >> 1, wc = w & 1;
  const int s4 = l >> 4;
  const int lx = l & 7;

  const int c = blockIdx.x;
  int g = (c * NPAIRS_P) >> 8;
  const int gend = ((c + 1) * NPAIRS_P) >> 8;

  // decode first (I,J) of chunk
  int I = 0, tri = 0;
  while (g - tri >= PANELS - I) { tri += PANELS - I; ++I; }
  int J = I + (g - tri);

  int a_base[4], b_base[4];
  #pragma unroll
  for (int mi = 0; mi < 4; ++mi)
    a_base[mi] = (wr * 64 + mi * 16 + (l & 15)) * 1024;
  #pragma unroll
  for (int ni = 0; ni < 4; ++ni)
    b_base[ni] = (wc * 64 + ni * 16 + (l & 15)) * 128;

  int curI = -1;

  for (; g < gend; ++g) {
    __builtin_amdgcn_s_barrier();        // all waves done reading prev tile
    const long cJ = (long)J * 128;
    if (I != curI) {                     // stage full A-panel (128 KB)
      curI = I;
      const long rI = (long)I * 128;
      #pragma unroll
      for (int i = 0; i < 32; ++i) {
        const int cc = i * 256 + t;      // chunk 0..8191
        const int r = cc >> 6, sp = cc & 63;
        const int s = sp ^ (r & 7);      // inverse-swizzled source slot
        const __hip_bfloat16* gp = reps + (rI + r) * D + s * 8;
        __builtin_amdgcn_global_load_lds((const AS1 void*)gp,
            (AS3 void*)(Abase + cc * 16), 16, 0, 0);
      }
    }
    // stage B K-tiles 0,1 (4 loads/thread each)
    #pragma unroll
    for (int kt = 0; kt < 2; ++kt)
      #pragma unroll
      for (int i = 0; i < 4; ++i) {
        const int cc = i * 256 + t;      // chunk 0..1023
        const int r = cc >> 3, sp = cc & 7;
        const int s = sp ^ (r & 7);
        const __hip_bfloat16* gp = reps + (cJ + r) * D + kt * 64 + s * 8;
        __builtin_amdgcn_global_load_lds((const AS1 void*)gp,
            (AS3 void*)(Bbase + kt * 16384 + cc * 16), 16, 0, 0);
      }
    asm volatile("s_waitcnt vmcnt(4)" ::: "memory");   // A + B0 landed (own)
    __builtin_amdgcn_s_barrier();                      // everyone's landed

    f32x4 acc[4][4];
    #pragma unroll
    for (int a = 0; a < 4; ++a)
      #pragma unroll
      for (int b = 0; b < 4; ++b) { f32x4 z = {0.f,0.f,0.f,0.f}; acc[a][b] = z; }

    bf16x8 aA[4][2], aB[4][2];
    #pragma unroll
    for (int mi = 0; mi < 4; ++mi)
      #pragma unroll
      for (int kk = 0; kk < 2; ++kk)
        aA[mi][kk] = *reinterpret_cast<const bf16x8*>(
            Abase + a_base[mi] + ((((kk << 2) | s4) ^ lx) << 4));

    #pragma unroll
    for (int k = 0; k < 8; ++k) {
      const int p = k & 1;
      bf16x8 (&acur)[4][2] = p ? aB : aA;
      bf16x8 (&anxt)[4][2] = p ? aA : aB;

      bf16x8 bv[4][2];
      #pragma unroll
      for (int ni = 0; ni < 4; ++ni)
        #pragma unroll
        for (int kk = 0; kk < 2; ++kk)
          bv[ni][kk] = *reinterpret_cast<const bf16x8*>(
              Bbase + p * 16384 + b_base[ni] + ((((kk << 2) | s4) ^ lx) << 4));
      if (k < 7) {   // prefetch next K-step's A-frags (read-only region)
        #pragma unroll
        for (int mi = 0; mi < 4; ++mi)
          #pragma unroll
          for (int kk = 0; kk < 2; ++kk)
            anxt[mi][kk] = *reinterpret_cast<const bf16x8*>(
                Abase + a_base[mi] +
                (((((k + 1) << 3) | (kk << 2) | s4) ^ lx) << 4));
      }
      __builtin_amdgcn_s_setprio(1);
      #pragma unroll
      for (int kk = 0; kk < 2; ++kk)
        #pragma unroll
        for (int mi = 0; mi < 4; ++mi)
          #pragma unroll
          for (int ni = 0; ni < 4; ++ni)
            acc[mi][ni] = __builtin_amdgcn_mfma_f32_16x16x32_bf16(
                acur[mi][kk], bv[ni][kk], acc[mi][ni], 0, 0, 0);
      __builtin_amdgcn_s_setprio(0);
      __builtin_amdgcn_s_barrier();      // all waves done reading B slot p
      if (k < 6) {                       // stage B[k+2] -> slot p
        #pragma unroll
        for (int i = 0; i < 4; ++i) {
          const int cc = i * 256 + t;
          const int r = cc >> 3, sp = cc & 7;
          const int s = sp ^ (r & 7);
          const __hip_bfloat16* gp = reps + (cJ + r) * D + (k + 2) * 64 + s * 8;
          __builtin_amdgcn_global_load_lds((const AS1 void*)gp,
              (AS3 void*)(Bbase + p * 16384 + cc * 16), 16, 0, 0);
        }
        asm volatile("s_waitcnt vmcnt(4)" ::: "memory");  // B[k+1] landed
      } else if (k == 6) {
        asm volatile("s_waitcnt vmcnt(0)" ::: "memory");  // B[7] landed
      }
      if (k < 7) __builtin_amdgcn_s_barrier();
    }

    // epilogue: e = exp(5*sim); in-wave row + col reductions, bf16 stores
    float rsum[4][4], csum[4];
    #pragma unroll
    for (int mi = 0; mi < 4; ++mi)
      #pragma unroll
      for (int j = 0; j < 4; ++j) rsum[mi][j] = 0.f;
    #pragma unroll
    for (int ni = 0; ni < 4; ++ni) csum[ni] = 0.f;
    #pragma unroll
    for (int mi = 0; mi < 4; ++mi)
      #pragma unroll
      for (int ni = 0; ni < 4; ++ni)
        #pragma unroll
        for (int j = 0; j < 4; ++j) {
          const float e = __expf(INV_T * acc[mi][ni][j]);
          rsum[mi][j] += e;
          csum[ni]   += e;
        }
    #pragma unroll
    for (int mi = 0; mi < 4; ++mi) {
      #pragma unroll
      for (int off = 1; off < 16; off <<= 1)
        #pragma unroll
        for (int j = 0; j < 4; ++j) rsum[mi][j] += __shfl_xor(rsum[mi][j], off, 64);
      if ((l & 15) == 0) {
        const long slot = 2 * J + wc;
        const int row = I * 128 + wr * 64 + mi * 16 + s4 * 4;
        #pragma unroll
        for (int j = 0; j < 4; ++j)
          S16[slot * TWO_N + row + j] = __float2bfloat16(rsum[mi][j]);
      }
    }
    #pragma unroll
    for (int off = 16; off < 64; off <<= 1)
      #pragma unroll
      for (int ni = 0; ni < 4; ++ni) csum[ni] += __shfl_xor(csum[ni], off, 64);
    if (I != J && l < 16) {
      const long slot = 2 * I + wr;
      const int col = J * 128 + wc * 64 + l;
      #pragma unroll
      for (int ni = 0; ni < 4; ++ni)
        S16[slot * TWO_N + col + ni * 16] = __float2bfloat16(csum[ni]);
    }

    if (++J == PANELS) { ++I; J = I; }   // advance in I-major order
  }
}

// ---------------- kernel 4: per-row log(denominator), block partials -------
__global__ __launch_bounds__(256) void rowlog_kernel(
    const __hip_bfloat16* __restrict__ S16, const float* __restrict__ diagexp,
    const float* __restrict__ scalars, float* __restrict__ blockpart)
{
  const int t = threadIdx.x;
  const int r = blockIdx.x * 256 + t;
  float s = 0.f;
  #pragma unroll 8
  for (int sl = 0; sl < NSLOT; ++sl)
    s += __bfloat162float(S16[(long)sl * TWO_N + r]);
  const float denom_fu = 2.0f * scalars[1];
  float v[1];
  v[0] = logf(s - diagexp[r] + denom_fu);
  block_reduce_bcast<1>(v);
  if (t == 0) blockpart[blockIdx.x] = v[0];
}

// ---------------- kernel 5: final scalar -----------------------------------
__global__ void final_kernel(const float* __restrict__ blockpart,
                             const float* __restrict__ scalars,
                             float* __restrict__ out)
{
  const int t = threadIdx.x;   // 64 threads
  float s = (t < TWO_N / 256) ? blockpart[t] : 0.f;
  #pragma unroll
  for (int off = 32; off; off >>= 1) s += __shfl_xor(s, off, 64);
  if (t == 0) out[0] = (s - 10.0f * scalars[0]) / (float)TWO_N;
}

extern "C" void kernel_launch(void* const* d_in, const int* in_sizes, int n_in,
                              void* d_out, int out_size, void* d_ws, size_t ws_size,
                              hipStream_t stream)
{
  const float* ei = (const float*)d_in[0];
  const float* ej = (const float*)d_in[1];
  const float* ek = (const float*)d_in[2];
  float* out = (float*)d_out;

  char* ws = (char*)d_ws;
  __hip_bfloat16* reps = (__hip_bfloat16*)ws;                          // 8 MB
  __hip_bfloat16* S16  = (__hip_bfloat16*)(ws + 8u * 1024 * 1024);     // 2 MB
  float* diagexp   = (float*)(ws + 10u * 1024 * 1024);                 // 32 KB
  float* pos_ij    = (float*)(ws + 10u * 1024 * 1024 + 32 * 1024);     // 16 KB
  float* exp_ik    = (float*)(ws + 10u * 1024 * 1024 + 48 * 1024);     // 16 KB
  float* scalars   = (float*)(ws + 10u * 1024 * 1024 + 64 * 1024);     // 8 B
  float* blockpart = (float*)(ws + 10u * 1024 * 1024 + 64 * 1024 + 256); // 128 B

  static const int kSmemBytes = 163840;   // full 160 KiB LDS (AITER precedent)
  (void)hipFuncSetAttribute((const void*)gemm_apanel_kernel,
                            hipFuncAttributeMaxDynamicSharedMemorySize,
                            kSmemBytes);

  normalize_kernel<<<N_ROWS, 256, 0, stream>>>(ei, ej, ek, reps, diagexp,
                                               pos_ij, exp_ik);
  scalar_kernel<<<1, 256, 0, stream>>>(pos_ij, exp_ik, scalars);
  gemm_apanel_kernel<<<GEMM_BLOCKS, 256, kSmemBytes, stream>>>(reps, S16);
  rowlog_kernel<<<TWO_N / 256, 256, 0, stream>>>(S16, diagexp, scalars,
                                                 blockpart);
  final_kernel<<<1, 64, 0, stream>>>(blockpart, scalars, out);
}

// Round 8
// 77.311 us; speedup vs baseline: 1.1954x; 1.1954x over previous
//
#include <hip/hip_runtime.h>
#include <hip/hip_bf16.h>
#include <math.h>

#define N_ROWS 4096
#define D 512
#define TWO_N 8192
#define TILE 128
#define BK 32
#define NKT 16               /* 512 / 32 K-tiles */
#define NJB 64               /* 8192 / 128 column blocks */
#define NPAIRS 2080          /* 64*65/2 upper-tri blocks */
#define INV_T 5.0f

typedef __attribute__((ext_vector_type(8))) __bf16 bf16x8;
typedef __attribute__((ext_vector_type(4))) float f32x4;
#define AS1 __attribute__((address_space(1)))
#define AS3 __attribute__((address_space(3)))

// ---------------- block reduction helper (broadcasts result) ----------------
template<int K>
__device__ inline void block_reduce_bcast(float (&v)[K]) {
  __shared__ float red[4][K];
  const int t = threadIdx.x;
  #pragma unroll
  for (int off = 32; off; off >>= 1)
    #pragma unroll
    for (int i = 0; i < K; ++i) v[i] += __shfl_xor(v[i], off, 64);
  __syncthreads();
  if ((t & 63) == 0)
    #pragma unroll
    for (int i = 0; i < K; ++i) red[t >> 6][i] = v[i];
  __syncthreads();
  #pragma unroll
  for (int i = 0; i < K; ++i) v[i] = red[0][i] + red[1][i] + red[2][i] + red[3][i];
}

// ---------------- kernel 1: normalize rows, emit bf16 reps + fp32 stats ----
__global__ __launch_bounds__(256) void normalize_kernel(
    const float* __restrict__ ei_, const float* __restrict__ ej_,
    const float* __restrict__ ek_,
    __hip_bfloat16* __restrict__ reps, float* __restrict__ diagexp,
    float* __restrict__ pos_ij, float* __restrict__ exp_ik)
{
  const int n = blockIdx.x;
  const int t = threadIdx.x;
  const long base = (long)n * D + 2 * t;
  const float2 ei = *reinterpret_cast<const float2*>(ei_ + base);
  const float2 ej = *reinterpret_cast<const float2*>(ej_ + base);
  const float2 ek = *reinterpret_cast<const float2*>(ek_ + base);

  float v[5];
  v[0] = ei.x * ei.x + ei.y * ei.y;
  v[1] = ej.x * ej.x + ej.y * ej.y;
  v[2] = ek.x * ek.x + ek.y * ek.y;
  v[3] = ei.x * ej.x + ei.y * ej.y;
  v[4] = ek.x * ei.x + ek.y * ei.y;
  block_reduce_bcast<5>(v);

  const float ni = fmaxf(sqrtf(v[0]), 1e-12f);
  const float nj = fmaxf(sqrtf(v[1]), 1e-12f);
  const float nk = fmaxf(sqrtf(v[2]), 1e-12f);
  const float invi = 1.0f / ni, invj = 1.0f / nj;

  __hip_bfloat162 pi, pj;
  pi.x = __float2bfloat16(ei.x * invi);
  pi.y = __float2bfloat16(ei.y * invi);
  pj.x = __float2bfloat16(ej.x * invj);
  pj.y = __float2bfloat16(ej.y * invj);
  *reinterpret_cast<__hip_bfloat162*>(reps + (long)n * D + 2 * t) = pi;
  *reinterpret_cast<__hip_bfloat162*>(reps + (long)(N_ROWS + n) * D + 2 * t) = pj;

  float q[2];
  {
    float f0 = __bfloat162float(pi.x), f1 = __bfloat162float(pi.y);
    q[0] = f0 * f0 + f1 * f1;
    f0 = __bfloat162float(pj.x); f1 = __bfloat162float(pj.y);
    q[1] = f0 * f0 + f1 * f1;
  }
  block_reduce_bcast<2>(q);

  if (t == 0) {
    diagexp[n]          = __expf(INV_T * q[0]);
    diagexp[N_ROWS + n] = __expf(INV_T * q[1]);
    pos_ij[n] = v[3] / (ni * nj);
    exp_ik[n] = __expf(INV_T * v[4] / (nk * ni));
  }
}

// ---------------- kernel 2: reduce the two scalars --------------------------
__global__ __launch_bounds__(256) void scalar_kernel(
    const float* __restrict__ pos_ij, const float* __restrict__ exp_ik,
    float* __restrict__ scalars)
{
  const int t = threadIdx.x;
  float v[2] = {0.f, 0.f};
  for (int i = t; i < N_ROWS; i += 256) { v[0] += pos_ij[i]; v[1] += exp_ik[i]; }
  block_reduce_bcast<2>(v);
  if (t == 0) { scalars[0] = v[0]; scalars[1] = v[1]; }
}

// ---------------- kernel 3: 128^2 BK=32 dbuf stage-ahead GEMM+exp+sums -----
// LDS 34.8 KB static -> 4 blocks/CU (16 waves/CU, 4/SIMD): cross-block TLP
// fills barrier/latency bubbles. K-loop: STAGE(k+1) issued BEFORE compute(k);
// single __syncthreads per K-tile (vmcnt(0) drain lands after ~700cyc MFMA).
// Region layout: [dbuf p][128 rows][4 slots x 16B]; swizzle slot^((row>>1)&3)
// (R5-refcheck'd: 2-way conflicts = free); inverse swizzle on global source.
__device__ __forceinline__ void stage_tile(
    const __hip_bfloat16* __restrict__ reps, char* region,
    long R0, int kt, int p, int t)
{
  #pragma unroll
  for (int s = 0; s < 2; ++s) {
    const int cc = s * 256 + t;          // chunk 0..511
    const int row = cc >> 2, slot = cc & 3;
    const int sl = slot ^ ((row >> 1) & 3);
    const __hip_bfloat16* g = reps + (R0 + row) * D + kt * 32 + sl * 8;
    __builtin_amdgcn_global_load_lds((const AS1 void*)g,
        (AS3 void*)(region + p * 8192 + cc * 16), 16, 0, 0);
  }
}

__global__ __launch_bounds__(256, 4) void gemm_expsum_kernel(
    const __hip_bfloat16* __restrict__ reps, float* __restrict__ S_partial)
{
  __shared__ __align__(16) char Ar[2 * 8192];
  __shared__ __align__(16) char Br[2 * 8192];
  __shared__ float rowbuf[2][TILE];
  __shared__ float colbuf[2][TILE];

  const int t = threadIdx.x;
  const int l = t & 63;
  const int w = t >> 6;          // wave 0..3
  const int wr = w >> 1, wc = w & 1;
  const int s4 = l >> 4;

  // XCD-aware bijective swizzle (2080 = 8*260), then triangular decode I<=J
  const int wg = (blockIdx.x & 7) * 260 + (blockIdx.x >> 3);
  int k = wg, I = 0;
  while (k >= NJB - I) { k -= NJB - I; ++I; }
  const int J = I + k;
  const long rI = (long)I * TILE;
  const long cJ = (long)J * TILE;

  // fragment byte offsets (dbuf term added at read): row*64 + swizzled slot
  // (row>>1)&3 == (l>>1)&3 independent of mi/ni (row bits 1-2 come from l)
  const int swz16 = ((s4 ^ ((l >> 1) & 3)) << 4);
  int a_off[4], b_off[4];
  #pragma unroll
  for (int mi = 0; mi < 4; ++mi)
    a_off[mi] = (wr * 64 + mi * 16 + (l & 15)) * 64 + swz16;
  #pragma unroll
  for (int ni = 0; ni < 4; ++ni)
    b_off[ni] = (wc * 64 + ni * 16 + (l & 15)) * 64 + swz16;

  f32x4 acc[4][4];
  #pragma unroll
  for (int a = 0; a < 4; ++a)
    #pragma unroll
    for (int b = 0; b < 4; ++b) { f32x4 z = {0.f, 0.f, 0.f, 0.f}; acc[a][b] = z; }

  // prologue: stage tile0 into buf0, wait (syncthreads drains vmcnt)
  stage_tile(reps, Ar, rI, 0, 0, t);
  stage_tile(reps, Br, cJ, 0, 0, t);
  __syncthreads();

  for (int kt = 0; kt < NKT; ++kt) {
    const int p = kt & 1;
    if (kt < NKT - 1) {                  // issue next tile BEFORE compute
      stage_tile(reps, Ar, rI, kt + 1, p ^ 1, t);
      stage_tile(reps, Br, cJ, kt + 1, p ^ 1, t);
    }
    bf16x8 av[4], bv[4];
    #pragma unroll
    for (int mi = 0; mi < 4; ++mi)
      av[mi] = *reinterpret_cast<const bf16x8*>(Ar + p * 8192 + a_off[mi]);
    #pragma unroll
    for (int ni = 0; ni < 4; ++ni)
      bv[ni] = *reinterpret_cast<const bf16x8*>(Br + p * 8192 + b_off[ni]);
    __builtin_amdgcn_s_setprio(1);
    #pragma unroll
    for (int mi = 0; mi < 4; ++mi)
      #pragma unroll
      for (int ni = 0; ni < 4; ++ni)
        acc[mi][ni] = __builtin_amdgcn_mfma_f32_16x16x32_bf16(
            av[mi], bv[ni], acc[mi][ni], 0, 0, 0);
    __builtin_amdgcn_s_setprio(0);
    __syncthreads();   // drains vmcnt(0): next tile landed; all done reading p
  }

  // epilogue: e = exp(5*sim); row-sums (rows of I) and col-sums (symmetry)
  float rsum[4][4], csum[4];
  #pragma unroll
  for (int mi = 0; mi < 4; ++mi)
    #pragma unroll
    for (int j = 0; j < 4; ++j) rsum[mi][j] = 0.f;
  #pragma unroll
  for (int ni = 0; ni < 4; ++ni) csum[ni] = 0.f;

  #pragma unroll
  for (int mi = 0; mi < 4; ++mi)
    #pragma unroll
    for (int ni = 0; ni < 4; ++ni)
      #pragma unroll
      for (int j = 0; j < 4; ++j) {
        const float e = __expf(INV_T * acc[mi][ni][j]);
        rsum[mi][j] += e;
        csum[ni]    += e;
      }

  #pragma unroll
  for (int mi = 0; mi < 4; ++mi) {
    #pragma unroll
    for (int off = 1; off < 16; off <<= 1)
      #pragma unroll
      for (int j = 0; j < 4; ++j) rsum[mi][j] += __shfl_xor(rsum[mi][j], off, 64);
    if ((l & 15) == 0) {
      const int rloc = wr * 64 + mi * 16 + s4 * 4;
      #pragma unroll
      for (int j = 0; j < 4; ++j) rowbuf[wc][rloc + j] = rsum[mi][j];
    }
  }
  #pragma unroll
  for (int off = 16; off < 64; off <<= 1)
    #pragma unroll
    for (int ni = 0; ni < 4; ++ni) csum[ni] += __shfl_xor(csum[ni], off, 64);
  if (l < 16) {
    #pragma unroll
    for (int ni = 0; ni < 4; ++ni)
      colbuf[wr][wc * 64 + ni * 16 + l] = csum[ni];
  }
  __syncthreads();

  if (t < TILE) {
    S_partial[(long)J * TWO_N + rI + t] = rowbuf[0][t] + rowbuf[1][t];
  } else if (I != J) {
    const int c = t - TILE;
    S_partial[(long)I * TWO_N + cJ + c] = colbuf[0][c] + colbuf[1][c];
  }
}

// ---------------- kernel 4: per-row log(denominator), block partials -------
__global__ __launch_bounds__(256) void rowlog_kernel(
    const float* __restrict__ S_partial, const float* __restrict__ diagexp,
    const float* __restrict__ scalars, float* __restrict__ blockpart)
{
  const int t = threadIdx.x;
  const int r = blockIdx.x * 256 + t;
  float s = 0.f;
  #pragma unroll 8
  for (int Jb = 0; Jb < NJB; ++Jb) s += S_partial[(long)Jb * TWO_N + r];
  const float denom_fu = 2.0f * scalars[1];
  float v[1];
  v[0] = logf(s - diagexp[r] + denom_fu);
  block_reduce_bcast<1>(v);
  if (t == 0) blockpart[blockIdx.x] = v[0];
}

// ---------------- kernel 5: final scalar -----------------------------------
__global__ void final_kernel(const float* __restrict__ blockpart,
                             const float* __restrict__ scalars,
                             float* __restrict__ out)
{
  const int t = threadIdx.x;   // 64 threads
  float s = (t < TWO_N / 256) ? blockpart[t] : 0.f;
  #pragma unroll
  for (int off = 32; off; off >>= 1) s += __shfl_xor(s, off, 64);
  if (t == 0) out[0] = (s - 10.0f * scalars[0]) / (float)TWO_N;
}

extern "C" void kernel_launch(void* const* d_in, const int* in_sizes, int n_in,
                              void* d_out, int out_size, void* d_ws, size_t ws_size,
                              hipStream_t stream)
{
  const float* ei = (const float*)d_in[0];
  const float* ej = (const float*)d_in[1];
  const float* ek = (const float*)d_in[2];
  float* out = (float*)d_out;

  char* ws = (char*)d_ws;
  __hip_bfloat16* reps = (__hip_bfloat16*)ws;                          // 8 MB
  float* S_partial = (float*)(ws + 8u * 1024 * 1024);                  // 2 MB
  float* diagexp   = (float*)(ws + 10u * 1024 * 1024);                 // 32 KB
  float* pos_ij    = (float*)(ws + 10u * 1024 * 1024 + 32 * 1024);     // 16 KB
  float* exp_ik    = (float*)(ws + 10u * 1024 * 1024 + 48 * 1024);     // 16 KB
  float* scalars   = (float*)(ws + 10u * 1024 * 1024 + 64 * 1024);     // 8 B
  float* blockpart = (float*)(ws + 10u * 1024 * 1024 + 64 * 1024 + 256); // 128 B

  normalize_kernel<<<N_ROWS, 256, 0, stream>>>(ei, ej, ek, reps, diagexp,
                                               pos_ij, exp_ik);
  scalar_kernel<<<1, 256, 0, stream>>>(pos_ij, exp_ik, scalars);
  gemm_expsum_kernel<<<NPAIRS, 256, 0, stream>>>(reps, S_partial);
  rowlog_kernel<<<TWO_N / 256, 256, 0, stream>>>(S_partial, diagexp, scalars,
                                                 blockpart);
  final_kernel<<<1, 64, 0, stream>>>(blockpart, scalars, out);
}

// Round 9
// 73.464 us; speedup vs baseline: 1.2580x; 1.0524x over previous
//
#include <hip/hip_runtime.h>
#include <hip/hip_bf16.h>
#include <math.h>

#define N_ROWS 4096
#define D 512
#define TWO_N 8192
#define TILE 128
#define NKT 16               /* 512 / 32 K-tiles */
#define NJB 64               /* 8192 / 128 column blocks */
#define NPAIRS 2080          /* 64*65/2 upper-tri blocks */
#define INV_T 5.0f

typedef __attribute__((ext_vector_type(8))) __bf16 bf16x8;
typedef __attribute__((ext_vector_type(8))) unsigned short u16x8;
typedef __attribute__((ext_vector_type(4))) float f32x4;
#define AS1 __attribute__((address_space(1)))
#define AS3 __attribute__((address_space(3)))

// ---------------- block reduction helper (broadcasts result) ----------------
template<int K>
__device__ inline void block_reduce_bcast(float (&v)[K]) {
  __shared__ float red[4][K];
  const int t = threadIdx.x;
  #pragma unroll
  for (int off = 32; off; off >>= 1)
    #pragma unroll
    for (int i = 0; i < K; ++i) v[i] += __shfl_xor(v[i], off, 64);
  __syncthreads();
  if ((t & 63) == 0)
    #pragma unroll
    for (int i = 0; i < K; ++i) red[t >> 6][i] = v[i];
  __syncthreads();
  #pragma unroll
  for (int i = 0; i < K; ++i) v[i] = red[0][i] + red[1][i] + red[2][i] + red[3][i];
}

// ---------------- kernel 1: wave-per-row normalize (no LDS, shfl-only) -----
// 1024 blocks x 256 threads; wave handles one row n; lane covers 8 f32.
__global__ __launch_bounds__(256) void normalize_kernel(
    const float* __restrict__ ei_, const float* __restrict__ ej_,
    const float* __restrict__ ek_,
    __hip_bfloat16* __restrict__ reps, float* __restrict__ diagexp,
    float* __restrict__ pos_ij, float* __restrict__ exp_ik)
{
  const int t = threadIdx.x;
  const int l = t & 63;
  const int n = blockIdx.x * 4 + (t >> 6);
  const long base = (long)n * D + l * 8;

  float ai[8], aj[8], ak[8];
  #pragma unroll
  for (int h = 0; h < 2; ++h) {
    const float4 vi = *reinterpret_cast<const float4*>(ei_ + base + h * 4);
    const float4 vj = *reinterpret_cast<const float4*>(ej_ + base + h * 4);
    const float4 vk = *reinterpret_cast<const float4*>(ek_ + base + h * 4);
    ai[h*4+0]=vi.x; ai[h*4+1]=vi.y; ai[h*4+2]=vi.z; ai[h*4+3]=vi.w;
    aj[h*4+0]=vj.x; aj[h*4+1]=vj.y; aj[h*4+2]=vj.z; aj[h*4+3]=vj.w;
    ak[h*4+0]=vk.x; ak[h*4+1]=vk.y; ak[h*4+2]=vk.z; ak[h*4+3]=vk.w;
  }

  float v[5] = {0.f, 0.f, 0.f, 0.f, 0.f};
  #pragma unroll
  for (int j = 0; j < 8; ++j) {
    v[0] += ai[j] * ai[j];
    v[1] += aj[j] * aj[j];
    v[2] += ak[j] * ak[j];
    v[3] += ai[j] * aj[j];
    v[4] += ak[j] * ai[j];
  }
  #pragma unroll
  for (int off = 32; off; off >>= 1)
    #pragma unroll
    for (int i = 0; i < 5; ++i) v[i] += __shfl_xor(v[i], off, 64);

  const float ni = fmaxf(sqrtf(v[0]), 1e-12f);
  const float nj = fmaxf(sqrtf(v[1]), 1e-12f);
  const float nk = fmaxf(sqrtf(v[2]), 1e-12f);
  const float invi = 1.0f / ni, invj = 1.0f / nj;

  u16x8 ui, uj;
  float q[2] = {0.f, 0.f};
  #pragma unroll
  for (int j = 0; j < 8; ++j) {
    const __hip_bfloat16 hi = __float2bfloat16(ai[j] * invi);
    const __hip_bfloat16 hj = __float2bfloat16(aj[j] * invj);
    ui[j] = *reinterpret_cast<const unsigned short*>(&hi);
    uj[j] = *reinterpret_cast<const unsigned short*>(&hj);
    const float fi = __bfloat162float(hi), fj = __bfloat162float(hj);
    q[0] += fi * fi;
    q[1] += fj * fj;
  }
  *reinterpret_cast<u16x8*>(reps + base) = ui;
  *reinterpret_cast<u16x8*>(reps + (long)N_ROWS * D + base) = uj;

  #pragma unroll
  for (int off = 32; off; off >>= 1)
    #pragma unroll
    for (int i = 0; i < 2; ++i) q[i] += __shfl_xor(q[i], off, 64);

  if (l == 0) {
    diagexp[n]          = __expf(INV_T * q[0]);
    diagexp[N_ROWS + n] = __expf(INV_T * q[1]);
    pos_ij[n] = v[3] / (ni * nj);
    exp_ik[n] = __expf(INV_T * v[4] / (nk * ni));
  }
}

// ---------------- kernel 2: reduce the two scalars --------------------------
__global__ __launch_bounds__(256) void scalar_kernel(
    const float* __restrict__ pos_ij, const float* __restrict__ exp_ik,
    float* __restrict__ scalars)
{
  const int t = threadIdx.x;
  float v[2] = {0.f, 0.f};
  for (int i = t; i < N_ROWS; i += 256) { v[0] += pos_ij[i]; v[1] += exp_ik[i]; }
  block_reduce_bcast<2>(v);
  if (t == 0) { scalars[0] = v[0]; scalars[1] = v[1]; }
}

// ---------------- kernel 3: 128^2 BK=32 3-buf depth-2 GEMM+exp+sums --------
// LDS 51.2 KB -> 3 blocks/CU (12 waves/CU). Depth-2 prefetch: iter k waits
// counted vmcnt(4) (T_k landed, T_{k+1} in flight), raw s_barrier (compiler
// fence, NO vmcnt drain), stages T_{k+2}. Loads get 2 K-tiles of compute to
// land -> latency hidden; the only per-tile serial cost is the barrier.
// Layout per buffer: [128 rows][4 slots x 16B]; slot swizzle ^((row>>1)&3)
// (R5/R8-verified, 2-way = free); inverse swizzle on global source.
__device__ __forceinline__ void stage_tile(
    const __hip_bfloat16* __restrict__ reps, char* region,
    long R0, int kt, int p, int t)
{
  #pragma unroll
  for (int s = 0; s < 2; ++s) {
    const int cc = s * 256 + t;          // chunk 0..511
    const int row = cc >> 2, slot = cc & 3;
    const int sl = slot ^ ((row >> 1) & 3);
    const __hip_bfloat16* g = reps + (R0 + row) * D + kt * 32 + sl * 8;
    __builtin_amdgcn_global_load_lds((const AS1 void*)g,
        (AS3 void*)(region + p * 8192 + cc * 16), 16, 0, 0);
  }
}

__global__ __launch_bounds__(256, 3) void gemm_expsum_kernel(
    const __hip_bfloat16* __restrict__ reps, float* __restrict__ S_partial)
{
  __shared__ __align__(16) char Ar[3 * 8192];
  __shared__ __align__(16) char Br[3 * 8192];
  __shared__ float rowbuf[2][TILE];
  __shared__ float colbuf[2][TILE];

  const int t = threadIdx.x;
  const int l = t & 63;
  const int w = t >> 6;          // wave 0..3
  const int wr = w >> 1, wc = w & 1;
  const int s4 = l >> 4;

  // XCD-aware bijective swizzle (2080 = 8*260), then triangular decode I<=J
  const int wg = (blockIdx.x & 7) * 260 + (blockIdx.x >> 3);
  int k = wg, I = 0;
  while (k >= NJB - I) { k -= NJB - I; ++I; }
  const int J = I + k;
  const long rI = (long)I * TILE;
  const long cJ = (long)J * TILE;

  // fragment byte offsets (buffer term added at read): row*64 + swizzled slot
  const int swz16 = ((s4 ^ ((l >> 1) & 3)) << 4);
  int a_off[4], b_off[4];
  #pragma unroll
  for (int mi = 0; mi < 4; ++mi)
    a_off[mi] = (wr * 64 + mi * 16 + (l & 15)) * 64 + swz16;
  #pragma unroll
  for (int ni = 0; ni < 4; ++ni)
    b_off[ni] = (wc * 64 + ni * 16 + (l & 15)) * 64 + swz16;

  f32x4 acc[4][4];
  #pragma unroll
  for (int a = 0; a < 4; ++a)
    #pragma unroll
    for (int b = 0; b < 4; ++b) { f32x4 z = {0.f, 0.f, 0.f, 0.f}; acc[a][b] = z; }

  // prologue: stage T0 (buf0), T1 (buf1) -> 8 outstanding
  stage_tile(reps, Ar, rI, 0, 0, t);
  stage_tile(reps, Br, cJ, 0, 0, t);
  stage_tile(reps, Ar, rI, 1, 1, t);
  stage_tile(reps, Br, cJ, 1, 1, t);

  #pragma unroll
  for (int kt = 0; kt < NKT; ++kt) {
    const int p = kt % 3;
    // T_kt landed when my 4 oldest loads (T_kt's) are done; barrier makes it
    // true for all waves AND retires everyone's reads of T_{kt-1}.
    if (kt == NKT - 1) asm volatile("s_waitcnt vmcnt(0)" ::: "memory");
    else               asm volatile("s_waitcnt vmcnt(4)" ::: "memory");
    asm volatile("s_barrier" ::: "memory");
    if (kt < NKT - 2) {                  // stage T_{kt+2} into buf (kt+2)%3
      stage_tile(reps, Ar, rI, kt + 2, (kt + 2) % 3, t);
      stage_tile(reps, Br, cJ, kt + 2, (kt + 2) % 3, t);
    }
    bf16x8 av[4], bv[4];
    #pragma unroll
    for (int mi = 0; mi < 4; ++mi)
      av[mi] = *reinterpret_cast<const bf16x8*>(Ar + p * 8192 + a_off[mi]);
    #pragma unroll
    for (int ni = 0; ni < 4; ++ni)
      bv[ni] = *reinterpret_cast<const bf16x8*>(Br + p * 8192 + b_off[ni]);
    __builtin_amdgcn_s_setprio(1);
    #pragma unroll
    for (int mi = 0; mi < 4; ++mi)
      #pragma unroll
      for (int ni = 0; ni < 4; ++ni)
        acc[mi][ni] = __builtin_amdgcn_mfma_f32_16x16x32_bf16(
            av[mi], bv[ni], acc[mi][ni], 0, 0, 0);
    __builtin_amdgcn_s_setprio(0);
  }

  // epilogue: e = exp(5*sim); row-sums (rows of I) and col-sums (symmetry)
  float rsum[4][4], csum[4];
  #pragma unroll
  for (int mi = 0; mi < 4; ++mi)
    #pragma unroll
    for (int j = 0; j < 4; ++j) rsum[mi][j] = 0.f;
  #pragma unroll
  for (int ni = 0; ni < 4; ++ni) csum[ni] = 0.f;

  #pragma unroll
  for (int mi = 0; mi < 4; ++mi)
    #pragma unroll
    for (int ni = 0; ni < 4; ++ni)
      #pragma unroll
      for (int j = 0; j < 4; ++j) {
        const float e = __expf(INV_T * acc[mi][ni][j]);
        rsum[mi][j] += e;
        csum[ni]    += e;
      }

  #pragma unroll
  for (int mi = 0; mi < 4; ++mi) {
    #pragma unroll
    for (int off = 1; off < 16; off <<= 1)
      #pragma unroll
      for (int j = 0; j < 4; ++j) rsum[mi][j] += __shfl_xor(rsum[mi][j], off, 64);
    if ((l & 15) == 0) {
      const int rloc = wr * 64 + mi * 16 + s4 * 4;
      #pragma unroll
      for (int j = 0; j < 4; ++j) rowbuf[wc][rloc + j] = rsum[mi][j];
    }
  }
  #pragma unroll
  for (int off = 16; off < 64; off <<= 1)
    #pragma unroll
    for (int ni = 0; ni < 4; ++ni) csum[ni] += __shfl_xor(csum[ni], off, 64);
  if (l < 16) {
    #pragma unroll
    for (int ni = 0; ni < 4; ++ni)
      colbuf[wr][wc * 64 + ni * 16 + l] = csum[ni];
  }
  __syncthreads();

  if (t < TILE) {
    S_partial[(long)J * TWO_N + rI + t] = rowbuf[0][t] + rowbuf[1][t];
  } else if (I != J) {
    const int c = t - TILE;
    S_partial[(long)I * TWO_N + cJ + c] = colbuf[0][c] + colbuf[1][c];
  }
}

// ---------------- kernel 4: per-row log(denominator), block partials -------
__global__ __launch_bounds__(256) void rowlog_kernel(
    const float* __restrict__ S_partial, const float* __restrict__ diagexp,
    const float* __restrict__ scalars, float* __restrict__ blockpart)
{
  const int t = threadIdx.x;
  const int r = blockIdx.x * 256 + t;
  float s = 0.f;
  #pragma unroll 8
  for (int Jb = 0; Jb < NJB; ++Jb) s += S_partial[(long)Jb * TWO_N + r];
  const float denom_fu = 2.0f * scalars[1];
  float v[1];
  v[0] = logf(s - diagexp[r] + denom_fu);
  block_reduce_bcast<1>(v);
  if (t == 0) blockpart[blockIdx.x] = v[0];
}

// ---------------- kernel 5: final scalar -----------------------------------
__global__ void final_kernel(const float* __restrict__ blockpart,
                             const float* __restrict__ scalars,
                             float* __restrict__ out)
{
  const int t = threadIdx.x;   // 64 threads
  float s = (t < TWO_N / 256) ? blockpart[t] : 0.f;
  #pragma unroll
  for (int off = 32; off; off >>= 1) s += __shfl_xor(s, off, 64);
  if (t == 0) out[0] = (s - 10.0f * scalars[0]) / (float)TWO_N;
}

extern "C" void kernel_launch(void* const* d_in, const int* in_sizes, int n_in,
                              void* d_out, int out_size, void* d_ws, size_t ws_size,
                              hipStream_t stream)
{
  const float* ei = (const float*)d_in[0];
  const float* ej = (const float*)d_in[1];
  const float* ek = (const float*)d_in[2];
  float* out = (float*)d_out;

  char* ws = (char*)d_ws;
  __hip_bfloat16* reps = (__hip_bfloat16*)ws;                          // 8 MB
  float* S_partial = (float*)(ws + 8u * 1024 * 1024);                  // 2 MB
  float* diagexp   = (float*)(ws + 10u * 1024 * 1024);                 // 32 KB
  float* pos_ij    = (float*)(ws + 10u * 1024 * 1024 + 32 * 1024);     // 16 KB
  float* exp_ik    = (float*)(ws + 10u * 1024 * 1024 + 48 * 1024);     // 16 KB
  float* scalars   = (float*)(ws + 10u * 1024 * 1024 + 64 * 1024);     // 8 B
  float* blockpart = (float*)(ws + 10u * 1024 * 1024 + 64 * 1024 + 256); // 128 B

  normalize_kernel<<<N_ROWS / 4, 256, 0, stream>>>(ei, ej, ek, reps, diagexp,
                                                   pos_ij, exp_ik);
  scalar_kernel<<<1, 256, 0, stream>>>(pos_ij, exp_ik, scalars);
  gemm_expsum_kernel<<<NPAIRS, 256, 0, stream>>>(reps, S_partial);
  rowlog_kernel<<<TWO_N / 256, 256, 0, stream>>>(S_partial, diagexp, scalars,
                                                 blockpart);
  final_kernel<<<1, 64, 0, stream>>>(blockpart, scalars, out);
}